// Round 9
// baseline (316.246 us; speedup 1.0000x reference)
//
#include <hip/hip_runtime.h>
#include <hip/hip_bf16.h>

#define H_ 16
#define KVH_ 4
#define D_ 128
#define L_ 2048
#define B_ 2
#define HID_ 2048
#define WIN_ 1024
#define NS_ 8
#define QKV_N 3072   // 2048 q + 512 k + 512 v fused

typedef __attribute__((ext_vector_type(8))) short short8;
typedef __attribute__((ext_vector_type(4))) float floatx4;

__device__ inline float bf16_to_f(unsigned short u) {
    union { unsigned int i; float f; } c; c.i = ((unsigned int)u) << 16; return c.f;
}
__device__ inline unsigned short f_to_bf16(float f) {
    __hip_bfloat16 h = __float2bfloat16(f);
    return *(unsigned short*)&h;
}

// ---------------------------------------------------------------------------
// Inline dtype detection (wave-uniform probe; see prior session notes).
// ---------------------------------------------------------------------------
__device__ inline int world_is_bf16(const unsigned short* hs_u) {
    int lane = threadIdx.x & 63;
    unsigned short u = hs_u[(lane & 31) * 2];
    int e = (u >> 7) & 0xFF;
    unsigned long long bad = __ballot(e > 130);
    return bad == 0ULL;
}
__device__ inline int pid_stride(const int* pids) { return (pids[1] == 0) ? 2 : 1; }

// ---------------------------------------------------------------------------
// Kernel A: dtype canonicalization. bf16 world: early-exit (GEMMs read the
// original tensors directly — saves a 75MB copy round-trip).
// ---------------------------------------------------------------------------
__global__ __launch_bounds__(256) void convert_all(const void* __restrict__ hs,
                                                   const void* __restrict__ Wq,
                                                   const void* __restrict__ Wk,
                                                   const void* __restrict__ Wv,
                                                   const void* __restrict__ Wo,
                                                   unsigned short* __restrict__ c_hs,
                                                   unsigned short* __restrict__ c_Wq,
                                                   unsigned short* __restrict__ c_Wk,
                                                   unsigned short* __restrict__ c_Wv,
                                                   unsigned short* __restrict__ c_Wo) {
    int isbf = world_is_bf16((const unsigned short*)hs);
    if (isbf) return;
    const int N0 = (B_ * L_ * HID_) / 4;        // hs   2,097,152
    const int N1 = (HID_ * HID_) / 4;           // Wq   1,048,576
    const int N2 = (KVH_ * D_ * HID_) / 4;      // Wk     262,144
    const int N3 = N2;                          // Wv
    const int N4 = N1;                          // Wo
    const int total = N0 + N1 + N2 + N3 + N4;
    for (int i = blockIdx.x * 256 + threadIdx.x; i < total; i += gridDim.x * 256) {
        int j = i;
        const void* src; unsigned short* dst;
        if (j < N0)              { src = hs; dst = c_hs; }
        else if ((j -= N0) < N1) { src = Wq; dst = c_Wq; }
        else if ((j -= N1) < N2) { src = Wk; dst = c_Wk; }
        else if ((j -= N2) < N3) { src = Wv; dst = c_Wv; }
        else                     { j -= N3; src = Wo; dst = c_Wo; }
        float4 f = ((const float4*)src)[j];
        ushort4 o4;
        o4.x = f_to_bf16(f.x); o4.y = f_to_bf16(f.y);
        o4.z = f_to_bf16(f.z); o4.w = f_to_bf16(f.w);
        ((ushort4*)dst)[j] = o4;
    }
}

// ---------------------------------------------------------------------------
// Kernel 1: per-batch rank scan + inverse poslist + per-state counts.
// ---------------------------------------------------------------------------
__global__ __launch_bounds__(256) void scan_kernel(const int* __restrict__ sid,
                                                   const int* __restrict__ pids,
                                                   int* __restrict__ rank,
                                                   int* __restrict__ poslist,
                                                   int* __restrict__ counts) {
    int stride = pid_stride(pids);
    int b = blockIdx.x;
    int t = threadIdx.x;
    __shared__ int cnt[256][NS_];
    __shared__ int pre[256][NS_];
    const int* s = sid + (size_t)b * L_ * stride;
    int myid[8];
#pragma unroll
    for (int i = 0; i < 8; i++) myid[i] = s[(t * 8 + i) * stride];
#pragma unroll
    for (int st = 0; st < NS_; st++) cnt[t][st] = 0;
#pragma unroll
    for (int i = 0; i < 8; i++) cnt[t][myid[i]]++;
    __syncthreads();
    for (int off = 1; off < 256; off <<= 1) {
        int add[NS_];
        if (t >= off)
#pragma unroll
            for (int st = 0; st < NS_; st++) add[st] = cnt[t - off][st];
        __syncthreads();
        if (t >= off)
#pragma unroll
            for (int st = 0; st < NS_; st++) cnt[t][st] += add[st];
        __syncthreads();
    }
#pragma unroll
    for (int st = 0; st < NS_; st++) pre[t][st] = t ? cnt[t - 1][st] : 0;
    if (t == 255)
#pragma unroll
        for (int st = 0; st < NS_; st++) counts[b * NS_ + st] = cnt[255][st];
    __syncthreads();
#pragma unroll
    for (int i = 0; i < 8; i++) {
        int sd = myid[i];
        int r = pre[t][sd]++;
        int pos = t * 8 + i;
        rank[b * L_ + pos] = r;
        poslist[((size_t)b * NS_ + sd) * L_ + r] = pos;
    }
}

// ---------------------------------------------------------------------------
// Kernel 2 (v9 = R7 loop + fused RoPE): BMx256 MFMA GEMM, BK=32, 4-deep LDS
// ring, counted vmcnt, 1 barrier/tile — R7's measured-best loop, unchanged.
//   MT=4 -> BM=256 (QKV, grid 12x16); MT=2 -> BM=128 (O-proj, grid 8x32).
//
// ROPE=true (QKV only): RoPE is fused into the epilogue, eliminating the
// separate rope kernel + a 50MB qkv round-trip. The rotate pair (d, d+64)
// spans two wave strips in the natural layout, so the weight rows are
// PERMUTED at staging — bijective within each 128-row head-block:
//   true(w,g,l) = (g&1)*16 + l + w*32 + (g>>1)*64   (w=row>>6,g=(row>>4)&3)
// so each lane's acc[.][g] / acc[.][g+2] hold exactly (d, d+64) with
// d = (g&1)*16 + l16 + (wc&1)*32. Rotation applied in fp32 registers
// (head-block < 20, i.e. q/k heads; v passes through), C-write scatters to
// TRUE columns: col = bn + (wc>>1)*128 + (g>>1)*64 + (g&1)*16 + (wc&1)*32
// + l16. Same map on both sides => bijective => exact.
//
// LDS rows 64 B (32 cols); swizzle: 16B slot s of row r holds global slot
// s ^ ((r>>1)&3) (keyed to LDS row — unaffected by the ROPE row remap);
// read XORs (l16>>1)&3. Linear LDS dst + pre-swizzled global src + swizzled
// read (both-sides-or-neither, m104/m231).
//
// Alt pointers: bf16 world reads ORIGINAL tensors (convert early-exited).
// ---------------------------------------------------------------------------
#define STAGE(gptr, ldsdst)                                                     \
    __builtin_amdgcn_global_load_lds(                                           \
        (const __attribute__((address_space(1))) unsigned int*)(gptr),          \
        (__attribute__((address_space(3))) unsigned int*)(ldsdst), 16, 0, 0)

#define SB __builtin_amdgcn_sched_barrier(0)

#define MFMA_P(P)                                                               \
    __builtin_amdgcn_s_setprio(1);                                              \
    _Pragma("unroll")                                                           \
    for (int m2 = 0; m2 < 2; ++m2)                                              \
        _Pragma("unroll")                                                       \
        for (int nt = 0; nt < 4; ++nt)                                          \
            acc[(P) * 2 + m2][nt] = __builtin_amdgcn_mfma_f32_16x16x32_bf16(    \
                fA[(P) * 2 + m2], fB[nt], acc[(P) * 2 + m2][nt], 0, 0, 0);      \
    __builtin_amdgcn_s_setprio(0)

template<int MT, bool ROPE>
__global__ __launch_bounds__(512, 1) void gemm_t(const unsigned short* __restrict__ Ac,
                                                 const unsigned short* __restrict__ B0c,
                                                 const unsigned short* __restrict__ B1c,
                                                 const unsigned short* __restrict__ B2c,
                                                 const unsigned short* __restrict__ Aa,
                                                 const unsigned short* __restrict__ B0a,
                                                 const unsigned short* __restrict__ B1a,
                                                 const unsigned short* __restrict__ B2a,
                                                 void* __restrict__ C,
                                                 int M, int N, int K,
                                                 int nb1, int nb2,
                                                 const unsigned short* __restrict__ hs_probe,
                                                 int c_mode,
                                                 const int* __restrict__ pids) {
    const int CH_A = MT / 2;                      // 8KB A-chunks per tile
    __shared__ unsigned short As[4][MT * 2048];   // [buf][BM rows x 32 cols]
    __shared__ unsigned short Bs[4][8192];        // [buf][256 rows x 32 cols]
    int tid = threadIdx.x;
    int wave = tid >> 6, lane = tid & 63;
    int quad = lane >> 4, l16 = lane & 15;
    int wr = wave >> 2, wc = wave & 3;            // 2 x 4 wave grid
    int bn_t = blockIdx.x;
    int bm = blockIdx.y * (MT * 64), bn = bn_t * 256;

    int isbf = world_is_bf16(hs_probe);
    const unsigned short* A  = isbf ? Aa  : Ac;
    const unsigned short* B0 = isbf ? B0a : B0c;
    const unsigned short* B1 = isbf ? B1a : B1c;
    const unsigned short* B2 = isbf ? B2a : B2c;

    const unsigned short* Bseg;
    int brow0;
    if (bn_t < nb1)      { Bseg = B0; brow0 = bn; }
    else if (bn_t < nb2) { Bseg = B1; brow0 = bn - nb1 * 256; }
    else                 { Bseg = B2; brow0 = bn - nb2 * 256; }

    // staging geometry: chunk = 128 rows x 32 cols = 8KB; thread writes LDS
    // linear tid*16B within the chunk; global src carries the swizzle.
    int sub = tid >> 2, slot = tid & 3;           // row 0..127, 16B slot 0..3
    int swz = slot ^ ((sub >> 1) & 3);
    int tsub = sub;                               // ROPE: permuted weight row
    if constexpr (ROPE) {
        int wdd = sub >> 6, gg = (sub >> 4) & 3, ll = sub & 15;
        tsub = (gg & 1) * 16 + ll + wdd * 32 + (gg >> 1) * 64;
    }
    unsigned int a_off[CH_A], b_off[2];
#pragma unroll
    for (int c = 0; c < CH_A; ++c)
        a_off[c] = (unsigned int)((bm + c * 128 + sub) * K + swz * 8);
#pragma unroll
    for (int c = 0; c < 2; ++c)
        b_off[c] = (unsigned int)((brow0 + c * 128 + tsub) * K + swz * 8);

    const int arow = wr * (MT * 32) + l16;        // A row base
    const int brr  = wc * 64 + l16;               // B row base
    const int xr   = (l16 >> 1) & 3;              // read-side swizzle

    floatx4 acc[2 * MT][4] = {};
    short8 fA[2 * MT], fB[4];
    const int KT = K >> 5;

    // prologue: stage tiles 0,1,2 into bufs 0,1,2 (B chunks then A chunks)
#pragma unroll
    for (int pt = 0; pt < 3; ++pt) {
        unsigned int kel = (unsigned int)pt * 32;
#pragma unroll
        for (int c = 0; c < 2; ++c)
            STAGE(Bseg + b_off[c] + kel, &Bs[pt][c * 4096 + tid * 8]);
#pragma unroll
        for (int c = 0; c < CH_A; ++c)
            STAGE(A + a_off[c] + kel, &As[pt][c * 4096 + tid * 8]);
    }

    for (int t = 0; t < KT; ++t) {
        const unsigned short* Ab = As[t & 3];
        const unsigned short* Bb = Bs[t & 3];
        int nbuf = (t + 3) & 3;
        int t3 = (t + 3 < KT) ? t + 3 : KT - 1;   // clamp: dead-buf restage
        unsigned int kel = (unsigned int)t3 * 32;

        // boundary: prove tile-t chunks (issued 3 tiles ago); pipe stays hot
        if constexpr (MT == 4) asm volatile("s_waitcnt vmcnt(8)" ::: "memory");
        else                   asm volatile("s_waitcnt vmcnt(6)" ::: "memory");
        __builtin_amdgcn_s_barrier();
        asm volatile("" ::: "memory");

        // all fragment reads upfront (first-needed first for in-order lgkm)
#pragma unroll
        for (int nt = 0; nt < 4; ++nt)
            fB[nt] = *(const short8*)&Bb[(brr + nt * 16) * 32 + ((quad ^ xr) * 8)];
#pragma unroll
        for (int mt = 0; mt < 2 * MT; ++mt)
            fA[mt] = *(const short8*)&Ab[(arow + mt * 16) * 32 + ((quad ^ xr) * 8)];
        SB;

        // stage tile t+3 into buf[(t+3)&3] (= consumed buf[(t-1)&3])
#pragma unroll
        for (int c = 0; c < 2; ++c)
            STAGE(Bseg + b_off[c] + kel, &Bs[nbuf][c * 4096 + tid * 8]);
#pragma unroll
        for (int c = 0; c < CH_A; ++c)
            STAGE(A + a_off[c] + kel, &As[nbuf][c * 4096 + tid * 8]);
        SB;

        // MFMA clusters (compiler inserts precise lgkm waits per cluster)
        MFMA_P(0); SB;
        MFMA_P(1);
        if constexpr (MT == 4) {
            SB; MFMA_P(2); SB; MFMA_P(3);
        }
    }
    asm volatile("s_waitcnt vmcnt(0)" ::: "memory");

    if constexpr (ROPE) {
        // fused RoPE epilogue: acc[a][g]/acc[a][g+2] hold the (d,d+64) pair
        int strideP = pid_stride(pids);
        int hb = (bn >> 7) + (wc >> 1);           // global head-block 0..23
        bool qk = (hb < 20);                      // q heads 0..15, k 16..19
        int w = wc & 1;
        int d0 = l16 + w * 32;                    // dim for g even
        const float kc = 0.015625f * 13.287712379549449f;  // (2/D)*log2(theta)
        float inv0 = exp2f(-(float)d0 * kc);
        float inv1 = exp2f(-(float)(d0 + 16) * kc);
        int colbase = bn + (wc >> 1) * 128 + w * 32 + l16;
#pragma unroll
        for (int a = 0; a < 2 * MT; ++a)
#pragma unroll
            for (int r = 0; r < 4; ++r) {
                int row = bm + wr * (MT * 32) + a * 16 + quad * 4 + r;
                float x0 = acc[a][0][r], x1 = acc[a][1][r];
                float x2 = acc[a][2][r], x3 = acc[a][3][r];
                if (qk) {
                    float pos = (float)pids[row * strideP];
                    float a0 = pos * inv0, a1 = pos * inv1;
                    float c0 = cosf(a0), s0 = sinf(a0);
                    float c1 = cosf(a1), s1 = sinf(a1);
                    float n0 = x0 * c0 - x2 * s0, n2 = x2 * c0 + x0 * s0;
                    float n1 = x1 * c1 - x3 * s1, n3 = x3 * c1 + x1 * s1;
                    x0 = n0; x1 = n1; x2 = n2; x3 = n3;
                }
                unsigned short* Cp = (unsigned short*)C + (size_t)row * N + colbase;
                Cp[0]  = f_to_bf16(x0);
                Cp[16] = f_to_bf16(x1);
                Cp[64] = f_to_bf16(x2);
                Cp[80] = f_to_bf16(x3);
            }
    } else {
        int cf32 = c_mode ? !isbf : 0;
        // C/D layout: col = lane&15, row = quad*4 + reg  [m89/m91 verified]
#pragma unroll
        for (int a = 0; a < 2 * MT; ++a)
#pragma unroll
            for (int g = 0; g < 4; ++g)
#pragma unroll
                for (int r = 0; r < 4; ++r) {
                    int row = bm + wr * (MT * 32) + a * 16 + quad * 4 + r;
                    int col = bn + wc * 64 + g * 16 + l16;
                    size_t idx = (size_t)row * N + col;
                    if (cf32) ((float*)C)[idx] = acc[a][g][r];
                    else      ((unsigned short*)C)[idx] = f_to_bf16(acc[a][g][r]);
                }
    }
}

// ---------------------------------------------------------------------------
// Kernel 4: MFMA flash attention (unchanged — verified fast).
// ---------------------------------------------------------------------------
__global__ __launch_bounds__(256, 4) void attn_mfma(const unsigned short* __restrict__ qkv,
                                                    const int* __restrict__ counts,
                                                    const int* __restrict__ poslist,
                                                    unsigned short* __restrict__ o) {
    int qt  = blockIdx.x & 127;
    int kvh = (blockIdx.x >> 7) & 3;
    int s   = (blockIdx.x >> 9) & 7;
    int b   = blockIdx.x >> 12;
    int n = counts[b * NS_ + s];
    if (qt * 16 >= n) return;
    const int* plist = poslist + ((size_t)b * NS_ + s) * L_;

    __shared__ short Ksh[32][136];
    __shared__ short Vsh[128][40];
    __shared__ short Psh[4][16][40];
    __shared__ int posq[16];

    int tid = threadIdx.x;
    int wave = tid >> 6, lane = tid & 63;
    int quad = lane >> 4, l16 = lane & 15;
    int h = kvh * 4 + wave;
    const float scale = 0.08838834764831845f;

    if (tid < 16) posq[tid] = plist[min(qt * 16 + tid, n - 1)];
    __syncthreads();

    short8 qf[4];
    {
        const unsigned short* gq =
            qkv + ((size_t)(b << 11) + posq[l16]) * QKV_N + h * D_;
#pragma unroll
        for (int kk = 0; kk < 4; kk++)
            qf[kk] = *(const short8*)(gq + kk * 32 + quad * 8);
    }

    float m_r[4], l_r[4];
    floatx4 Ov[8];
#pragma unroll
    for (int r4 = 0; r4 < 4; r4++) { m_r[r4] = -1e30f; l_r[r4] = 0.f; }
#pragma unroll
    for (int nt = 0; nt < 8; nt++) Ov[nt] = (floatx4){0.f, 0.f, 0.f, 0.f};

    int c0 = max(0, (qt * 16 - WIN_) >> 5);
    int nch = ((qt * 16 + 15) >> 5) + 1;

    int r = tid >> 3, seg = tid & 7;
    int vc = r ^ ((seg & 3) << 3);
    short8 kr0, kr1, vr0, vr1;
    {
        int kpos = plist[min(c0 * 32 + r, n - 1)];
        size_t base = ((size_t)(b << 11) + kpos) * QKV_N + 2048 + kvh * D_ + seg * 16;
        kr0 = *(const short8*)(qkv + base);
        kr1 = *(const short8*)(qkv + base + 8);
        vr0 = *(const short8*)(qkv + base + 512);
        vr1 = *(const short8*)(qkv + base + 520);
    }

    for (int c = c0; c < nch; c++) {
        *(short8*)&Ksh[r][seg * 16]     = kr0;
        *(short8*)&Ksh[r][seg * 16 + 8] = kr1;
#pragma unroll
        for (int e = 0; e < 8; e++) Vsh[seg * 16 + e][vc] = vr0[e];
#pragma unroll
        for (int e = 0; e < 8; e++) Vsh[seg * 16 + 8 + e][vc] = vr1[e];
        __syncthreads();

        if (c + 1 < nch) {
            int kpos = plist[min((c + 1) * 32 + r, n - 1)];
            size_t base = ((size_t)(b << 11) + kpos) * QKV_N + 2048 + kvh * D_ + seg * 16;
            kr0 = *(const short8*)(qkv + base);
            kr1 = *(const short8*)(qkv + base + 8);
            vr0 = *(const short8*)(qkv + base + 512);
            vr1 = *(const short8*)(qkv + base + 520);
        }

        floatx4 s0 = (floatx4){0.f, 0.f, 0.f, 0.f};
        floatx4 s1 = (floatx4){0.f, 0.f, 0.f, 0.f};
#pragma unroll
        for (int kk = 0; kk < 4; kk++) {
            short8 kfa = *(const short8*)&Ksh[l16][kk * 32 + quad * 8];
            s0 = __builtin_amdgcn_mfma_f32_16x16x32_bf16(qf[kk], kfa, s0, 0, 0, 0);
        }
#pragma unroll
        for (int kk = 0; kk < 4; kk++) {
            short8 kfb = *(const short8*)&Ksh[16 + l16][kk * 32 + quad * 8];
            s1 = __builtin_amdgcn_mfma_f32_16x16x32_bf16(qf[kk], kfb, s1, 0, 0, 0);
        }

        int kr0i = c * 32 + l16, kr1i = kr0i + 16;
        float x0[4], x1[4], rmax[4];
#pragma unroll
        for (int r4 = 0; r4 < 4; r4++) {
            int qr = qt * 16 + quad * 4 + r4;
            bool mk0 = (kr0i <= qr) && (kr0i >= qr - WIN_);
            bool mk1 = (kr1i <= qr) && (kr1i >= qr - WIN_);
            x0[r4] = mk0 ? s0[r4] * scale : -1e30f;
            x1[r4] = mk1 ? s1[r4] * scale : -1e30f;
            rmax[r4] = fmaxf(x0[r4], x1[r4]);
        }
#pragma unroll
        for (int st = 1; st <= 8; st <<= 1)
#pragma unroll
            for (int r4 = 0; r4 < 4; r4++)
                rmax[r4] = fmaxf(rmax[r4], __shfl_xor(rmax[r4], st, 64));
        float al[4], psum[4];
#pragma unroll
        for (int r4 = 0; r4 < 4; r4++) {
            float nm = fmaxf(m_r[r4], rmax[r4]);
            al[r4] = __expf(m_r[r4] - nm);
            m_r[r4] = nm;
            x0[r4] = (x0[r4] > -1e29f) ? __expf(x0[r4] - nm) : 0.f;
            x1[r4] = (x1[r4] > -1e29f) ? __expf(x1[r4] - nm) : 0.f;
            psum[r4] = x0[r4] + x1[r4];
        }
#pragma unroll
        for (int st = 1; st <= 8; st <<= 1)
#pragma unroll
            for (int r4 = 0; r4 < 4; r4++)
                psum[r4] += __shfl_xor(psum[r4], st, 64);
#pragma unroll
        for (int r4 = 0; r4 < 4; r4++) l_r[r4] = l_r[r4] * al[r4] + psum[r4];
#pragma unroll
        for (int nt = 0; nt < 8; nt++)
#pragma unroll
            for (int r4 = 0; r4 < 4; r4++) Ov[nt][r4] *= al[r4];

#pragma unroll
        for (int r4 = 0; r4 < 4; r4++) {
            Psh[wave][quad * 4 + r4][l16]      = (short)f_to_bf16(x0[r4]);
            Psh[wave][quad * 4 + r4][16 + l16] = (short)f_to_bf16(x1[r4]);
        }
        short8 pf = *(const short8*)&Psh[wave][l16][quad * 8];

#pragma unroll
        for (int nt = 0; nt < 8; nt++) {
            short8 vf = *(const short8*)&Vsh[nt * 16 + l16][(quad ^ (nt & 3)) * 8];
            Ov[nt] = __builtin_amdgcn_mfma_f32_16x16x32_bf16(pf, vf, Ov[nt], 0, 0, 0);
        }
        __syncthreads();
    }

    float inv_r[4];
    int pos_r[4], qvalid[4];
#pragma unroll
    for (int r4 = 0; r4 < 4; r4++) {
        int qr = qt * 16 + quad * 4 + r4;
        qvalid[r4] = (qr < n);
        inv_r[r4] = 1.f / l_r[r4];
        pos_r[r4] = posq[quad * 4 + r4];
    }
#pragma unroll
    for (int nt = 0; nt < 8; nt++)
#pragma unroll
        for (int r4 = 0; r4 < 4; r4++)
            if (qvalid[r4])
                o[(((size_t)(b << 11) + pos_r[r4]) * H_ + h) * D_ + nt * 16 + l16] =
                    f_to_bf16(Ov[nt][r4] * inv_r[r4]);
}

// ---------------------------------------------------------------------------
extern "C" void kernel_launch(void* const* d_in, const int* in_sizes, int n_in,
                              void* d_out, int out_size, void* d_ws, size_t ws_size,
                              hipStream_t stream) {
    const void* hs = d_in[0];
    const void* Wq = d_in[1];
    const void* Wk = d_in[2];
    const void* Wv = d_in[3];
    const void* Wo = d_in[4];
    const int* sid  = (const int*)d_in[5];
    const int* pids = (const int*)d_in[6];

    const int M = B_ * L_;  // 4096
    char* w = (char*)d_ws;
    unsigned short* qkv  = (unsigned short*)(w + 256);          // 25,165,824
    unsigned short* o_b  = (unsigned short*)(w + 25166080);     // 16,777,216
    unsigned short* c_hs = (unsigned short*)(w + 41943296);     // 16,777,216
    unsigned short* c_Wq = (unsigned short*)(w + 58720512);     //  8,388,608
    unsigned short* c_Wk = (unsigned short*)(w + 67109120);     //  2,097,152
    unsigned short* c_Wv = (unsigned short*)(w + 69206272);     //  2,097,152
    unsigned short* c_Wo = (unsigned short*)(w + 71303424);     //  8,388,608
    int* rank            = (int*)(w + 79692032);                //     16,384
    int* plist           = (int*)(w + 79708416);                //    131,072
    int* counts          = (int*)(w + 79839488);                //        256

    const unsigned short* hs_probe = (const unsigned short*)hs;

    // dtype canonicalization (fp32 world only; bf16 world early-exits)
    convert_all<<<2048, 256, 0, stream>>>(hs, Wq, Wk, Wv, Wo,
                                          c_hs, c_Wq, c_Wk, c_Wv, c_Wo);

    scan_kernel<<<B_, 256, 0, stream>>>(sid, pids, rank, plist, counts);

    // fused QKV projection + RoPE: BM=256, N = 3072,
    // 256-col tiles [0,8)=Wq, [8,10)=Wk, [10,12)=Wv
    gemm_t<4, true><<<dim3(QKV_N / 256, M / 256), 512, 0, stream>>>(
        c_hs, c_Wq, c_Wk, c_Wv,
        (const unsigned short*)hs, (const unsigned short*)Wq,
        (const unsigned short*)Wk, (const unsigned short*)Wv,
        qkv, M, QKV_N, HID_, 8, 10, hs_probe, 0, pids);

    attn_mfma<<<B_ * NS_ * KVH_ * (L_ / 16), 256, 0, stream>>>(qkv, counts, plist, o_b);

    // O-proj: BM=128 -> 8 x 32 = 256 blocks
    gemm_t<2, false><<<dim3(HID_ / 256, M / 128), 512, 0, stream>>>(
        o_b, c_Wo, c_Wo, c_Wo,
        o_b, (const unsigned short*)Wo, (const unsigned short*)Wo,
        (const unsigned short*)Wo,
        d_out, M, HID_, HID_, 1 << 30, 1 << 30, hs_probe, 1, pids);
}

// Round 10
// 278.044 us; speedup vs baseline: 1.1374x; 1.1374x over previous
//
#include <hip/hip_runtime.h>
#include <hip/hip_bf16.h>

#define H_ 16
#define KVH_ 4
#define D_ 128
#define L_ 2048
#define B_ 2
#define HID_ 2048
#define WIN_ 1024
#define NS_ 8
#define QKV_N 3072   // 2048 q + 512 k + 512 v fused

typedef __attribute__((ext_vector_type(8))) short short8;
typedef __attribute__((ext_vector_type(4))) float floatx4;

__device__ inline float bf16_to_f(unsigned short u) {
    union { unsigned int i; float f; } c; c.i = ((unsigned int)u) << 16; return c.f;
}
__device__ inline unsigned short f_to_bf16(float f) {
    __hip_bfloat16 h = __float2bfloat16(f);
    return *(unsigned short*)&h;
}

// ---------------------------------------------------------------------------
// Inline dtype detection (wave-uniform probe; see prior session notes).
// ---------------------------------------------------------------------------
__device__ inline int world_is_bf16(const unsigned short* hs_u) {
    int lane = threadIdx.x & 63;
    unsigned short u = hs_u[(lane & 31) * 2];
    int e = (u >> 7) & 0xFF;
    unsigned long long bad = __ballot(e > 130);
    return bad == 0ULL;
}
__device__ inline int pid_stride(const int* pids) { return (pids[1] == 0) ? 2 : 1; }

// ---------------------------------------------------------------------------
// Kernel A: dtype canonicalization. bf16 world: early-exit (GEMMs read the
// original tensors directly — saves a 75MB copy round-trip).
// ---------------------------------------------------------------------------
__global__ __launch_bounds__(256) void convert_all(const void* __restrict__ hs,
                                                   const void* __restrict__ Wq,
                                                   const void* __restrict__ Wk,
                                                   const void* __restrict__ Wv,
                                                   const void* __restrict__ Wo,
                                                   unsigned short* __restrict__ c_hs,
                                                   unsigned short* __restrict__ c_Wq,
                                                   unsigned short* __restrict__ c_Wk,
                                                   unsigned short* __restrict__ c_Wv,
                                                   unsigned short* __restrict__ c_Wo) {
    int isbf = world_is_bf16((const unsigned short*)hs);
    if (isbf) return;
    const int N0 = (B_ * L_ * HID_) / 4;        // hs   2,097,152
    const int N1 = (HID_ * HID_) / 4;           // Wq   1,048,576
    const int N2 = (KVH_ * D_ * HID_) / 4;      // Wk     262,144
    const int N3 = N2;                          // Wv
    const int N4 = N1;                          // Wo
    const int total = N0 + N1 + N2 + N3 + N4;
    for (int i = blockIdx.x * 256 + threadIdx.x; i < total; i += gridDim.x * 256) {
        int j = i;
        const void* src; unsigned short* dst;
        if (j < N0)              { src = hs; dst = c_hs; }
        else if ((j -= N0) < N1) { src = Wq; dst = c_Wq; }
        else if ((j -= N1) < N2) { src = Wk; dst = c_Wk; }
        else if ((j -= N2) < N3) { src = Wv; dst = c_Wv; }
        else                     { j -= N3; src = Wo; dst = c_Wo; }
        float4 f = ((const float4*)src)[j];
        ushort4 o4;
        o4.x = f_to_bf16(f.x); o4.y = f_to_bf16(f.y);
        o4.z = f_to_bf16(f.z); o4.w = f_to_bf16(f.w);
        ((ushort4*)dst)[j] = o4;
    }
}

// ---------------------------------------------------------------------------
// Kernel 1: per-batch rank scan + inverse poslist + per-state counts.
// ---------------------------------------------------------------------------
__global__ __launch_bounds__(256) void scan_kernel(const int* __restrict__ sid,
                                                   const int* __restrict__ pids,
                                                   int* __restrict__ rank,
                                                   int* __restrict__ poslist,
                                                   int* __restrict__ counts) {
    int stride = pid_stride(pids);
    int b = blockIdx.x;
    int t = threadIdx.x;
    __shared__ int cnt[256][NS_];
    __shared__ int pre[256][NS_];
    const int* s = sid + (size_t)b * L_ * stride;
    int myid[8];
#pragma unroll
    for (int i = 0; i < 8; i++) myid[i] = s[(t * 8 + i) * stride];
#pragma unroll
    for (int st = 0; st < NS_; st++) cnt[t][st] = 0;
#pragma unroll
    for (int i = 0; i < 8; i++) cnt[t][myid[i]]++;
    __syncthreads();
    for (int off = 1; off < 256; off <<= 1) {
        int add[NS_];
        if (t >= off)
#pragma unroll
            for (int st = 0; st < NS_; st++) add[st] = cnt[t - off][st];
        __syncthreads();
        if (t >= off)
#pragma unroll
            for (int st = 0; st < NS_; st++) cnt[t][st] += add[st];
        __syncthreads();
    }
#pragma unroll
    for (int st = 0; st < NS_; st++) pre[t][st] = t ? cnt[t - 1][st] : 0;
    if (t == 255)
#pragma unroll
        for (int st = 0; st < NS_; st++) counts[b * NS_ + st] = cnt[255][st];
    __syncthreads();
#pragma unroll
    for (int i = 0; i < 8; i++) {
        int sd = myid[i];
        int r = pre[t][sd]++;
        int pos = t * 8 + i;
        rank[b * L_ + pos] = r;
        poslist[((size_t)b * NS_ + sd) * L_ + r] = pos;
    }
}

// ---------------------------------------------------------------------------
// Kernel 2 (v10 = R7 loop + fused RoPE, FAST TRIG): BMx256 MFMA GEMM, BK=32,
// 4-deep LDS ring, counted vmcnt, 1 barrier/tile — R7's measured-best loop.
//   MT=4 -> BM=256 (QKV, grid 12x16); MT=2 -> BM=128 (O-proj, grid 8x32).
//
// ROPE=true (QKV only): RoPE fused into the epilogue (mapping VALIDATED in
// R9 — absmax clean). R9's +37us epilogue cost was libm cosf/sinf (precise
// __ocml blobs, ~100s of cycles) at 1 block/CU with no TLP to hide them.
// v10: __cosf/__sinf (HW v_cos/v_sin, ~7cy; err ~1e-4 << bf16 quantum) and
// pids loads hoisted into a batched pre-pass so the 32 L2-hot loads pipeline.
//
// Weight-row permutation at staging (bijective per 128-row head-block):
//   true(w,g,l) = (g&1)*16 + l + w*32 + (g>>1)*64
// => lane's acc[.][g]/acc[.][g+2] hold the (d, d+64) rotate pair with
// d = (g&1)*16 + l16 + (wc&1)*32. C-write scatters to TRUE columns.
//
// LDS rows 64 B (32 cols); swizzle: 16B slot s of row r holds global slot
// s ^ ((r>>1)&3); read XORs (l16>>1)&3 (both-sides-or-neither, m104/m231).
// Alt pointers: bf16 world reads ORIGINAL tensors (convert early-exited).
// ---------------------------------------------------------------------------
#define STAGE(gptr, ldsdst)                                                     \
    __builtin_amdgcn_global_load_lds(                                           \
        (const __attribute__((address_space(1))) unsigned int*)(gptr),          \
        (__attribute__((address_space(3))) unsigned int*)(ldsdst), 16, 0, 0)

#define SB __builtin_amdgcn_sched_barrier(0)

#define MFMA_P(P)                                                               \
    __builtin_amdgcn_s_setprio(1);                                              \
    _Pragma("unroll")                                                           \
    for (int m2 = 0; m2 < 2; ++m2)                                              \
        _Pragma("unroll")                                                       \
        for (int nt = 0; nt < 4; ++nt)                                          \
            acc[(P) * 2 + m2][nt] = __builtin_amdgcn_mfma_f32_16x16x32_bf16(    \
                fA[(P) * 2 + m2], fB[nt], acc[(P) * 2 + m2][nt], 0, 0, 0);      \
    __builtin_amdgcn_s_setprio(0)

template<int MT, bool ROPE>
__global__ __launch_bounds__(512, 1) void gemm_t(const unsigned short* __restrict__ Ac,
                                                 const unsigned short* __restrict__ B0c,
                                                 const unsigned short* __restrict__ B1c,
                                                 const unsigned short* __restrict__ B2c,
                                                 const unsigned short* __restrict__ Aa,
                                                 const unsigned short* __restrict__ B0a,
                                                 const unsigned short* __restrict__ B1a,
                                                 const unsigned short* __restrict__ B2a,
                                                 void* __restrict__ C,
                                                 int M, int N, int K,
                                                 int nb1, int nb2,
                                                 const unsigned short* __restrict__ hs_probe,
                                                 int c_mode,
                                                 const int* __restrict__ pids) {
    const int CH_A = MT / 2;                      // 8KB A-chunks per tile
    __shared__ unsigned short As[4][MT * 2048];   // [buf][BM rows x 32 cols]
    __shared__ unsigned short Bs[4][8192];        // [buf][256 rows x 32 cols]
    int tid = threadIdx.x;
    int wave = tid >> 6, lane = tid & 63;
    int quad = lane >> 4, l16 = lane & 15;
    int wr = wave >> 2, wc = wave & 3;            // 2 x 4 wave grid
    int bn_t = blockIdx.x;
    int bm = blockIdx.y * (MT * 64), bn = bn_t * 256;

    int isbf = world_is_bf16(hs_probe);
    const unsigned short* A  = isbf ? Aa  : Ac;
    const unsigned short* B0 = isbf ? B0a : B0c;
    const unsigned short* B1 = isbf ? B1a : B1c;
    const unsigned short* B2 = isbf ? B2a : B2c;

    const unsigned short* Bseg;
    int brow0;
    if (bn_t < nb1)      { Bseg = B0; brow0 = bn; }
    else if (bn_t < nb2) { Bseg = B1; brow0 = bn - nb1 * 256; }
    else                 { Bseg = B2; brow0 = bn - nb2 * 256; }

    // staging geometry: chunk = 128 rows x 32 cols = 8KB; thread writes LDS
    // linear tid*16B within the chunk; global src carries the swizzle.
    int sub = tid >> 2, slot = tid & 3;           // row 0..127, 16B slot 0..3
    int swz = slot ^ ((sub >> 1) & 3);
    int tsub = sub;                               // ROPE: permuted weight row
    if constexpr (ROPE) {
        int wdd = sub >> 6, gg = (sub >> 4) & 3, ll = sub & 15;
        tsub = (gg & 1) * 16 + ll + wdd * 32 + (gg >> 1) * 64;
    }
    unsigned int a_off[CH_A], b_off[2];
#pragma unroll
    for (int c = 0; c < CH_A; ++c)
        a_off[c] = (unsigned int)((bm + c * 128 + sub) * K + swz * 8);
#pragma unroll
    for (int c = 0; c < 2; ++c)
        b_off[c] = (unsigned int)((brow0 + c * 128 + tsub) * K + swz * 8);

    const int arow = wr * (MT * 32) + l16;        // A row base
    const int brr  = wc * 64 + l16;               // B row base
    const int xr   = (l16 >> 1) & 3;              // read-side swizzle

    floatx4 acc[2 * MT][4] = {};
    short8 fA[2 * MT], fB[4];
    const int KT = K >> 5;

    // prologue: stage tiles 0,1,2 into bufs 0,1,2 (B chunks then A chunks)
#pragma unroll
    for (int pt = 0; pt < 3; ++pt) {
        unsigned int kel = (unsigned int)pt * 32;
#pragma unroll
        for (int c = 0; c < 2; ++c)
            STAGE(Bseg + b_off[c] + kel, &Bs[pt][c * 4096 + tid * 8]);
#pragma unroll
        for (int c = 0; c < CH_A; ++c)
            STAGE(A + a_off[c] + kel, &As[pt][c * 4096 + tid * 8]);
    }

    for (int t = 0; t < KT; ++t) {
        const unsigned short* Ab = As[t & 3];
        const unsigned short* Bb = Bs[t & 3];
        int nbuf = (t + 3) & 3;
        int t3 = (t + 3 < KT) ? t + 3 : KT - 1;   // clamp: dead-buf restage
        unsigned int kel = (unsigned int)t3 * 32;

        // boundary: prove tile-t chunks (issued 3 tiles ago); pipe stays hot
        if constexpr (MT == 4) asm volatile("s_waitcnt vmcnt(8)" ::: "memory");
        else                   asm volatile("s_waitcnt vmcnt(6)" ::: "memory");
        __builtin_amdgcn_s_barrier();
        asm volatile("" ::: "memory");

        // all fragment reads upfront (first-needed first for in-order lgkm)
#pragma unroll
        for (int nt = 0; nt < 4; ++nt)
            fB[nt] = *(const short8*)&Bb[(brr + nt * 16) * 32 + ((quad ^ xr) * 8)];
#pragma unroll
        for (int mt = 0; mt < 2 * MT; ++mt)
            fA[mt] = *(const short8*)&Ab[(arow + mt * 16) * 32 + ((quad ^ xr) * 8)];
        SB;

        // stage tile t+3 into buf[(t+3)&3] (= consumed buf[(t-1)&3])
#pragma unroll
        for (int c = 0; c < 2; ++c)
            STAGE(Bseg + b_off[c] + kel, &Bs[nbuf][c * 4096 + tid * 8]);
#pragma unroll
        for (int c = 0; c < CH_A; ++c)
            STAGE(A + a_off[c] + kel, &As[nbuf][c * 4096 + tid * 8]);
        SB;

        // MFMA clusters (compiler inserts precise lgkm waits per cluster)
        MFMA_P(0); SB;
        MFMA_P(1);
        if constexpr (MT == 4) {
            SB; MFMA_P(2); SB; MFMA_P(3);
        }
    }
    asm volatile("s_waitcnt vmcnt(0)" ::: "memory");

    if constexpr (ROPE) {
        // fused RoPE epilogue: acc[a][g]/acc[a][g+2] hold the (d,d+64) pair
        int strideP = pid_stride(pids);
        int hb = (bn >> 7) + (wc >> 1);           // global head-block 0..23
        bool qk = (hb < 20);                      // q heads 0..15, k 16..19
        int w = wc & 1;
        int d0 = l16 + w * 32;                    // dim for g even
        const float kc = 0.015625f * 13.287712379549449f;  // (2/D)*log2(theta)
        float inv0 = exp2f(-(float)d0 * kc);
        float inv1 = exp2f(-(float)(d0 + 16) * kc);
        int colbase = bn + (wc >> 1) * 128 + w * 32 + l16;

        // batched pos loads (L2-hot; pipelined, away from the trig)
        float posv[2 * MT][4];
        if (qk) {
#pragma unroll
            for (int a = 0; a < 2 * MT; ++a)
#pragma unroll
                for (int r = 0; r < 4; ++r) {
                    int row = bm + wr * (MT * 32) + a * 16 + quad * 4 + r;
                    posv[a][r] = (float)pids[row * strideP];
                }
        }
#pragma unroll
        for (int a = 0; a < 2 * MT; ++a)
#pragma unroll
            for (int r = 0; r < 4; ++r) {
                int row = bm + wr * (MT * 32) + a * 16 + quad * 4 + r;
                float x0 = acc[a][0][r], x1 = acc[a][1][r];
                float x2 = acc[a][2][r], x3 = acc[a][3][r];
                if (qk) {
                    float a0 = posv[a][r] * inv0, a1 = posv[a][r] * inv1;
                    float c0 = __cosf(a0), s0 = __sinf(a0);   // HW v_cos/v_sin
                    float c1 = __cosf(a1), s1 = __sinf(a1);
                    float n0 = x0 * c0 - x2 * s0, n2 = x2 * c0 + x0 * s0;
                    float n1 = x1 * c1 - x3 * s1, n3 = x3 * c1 + x1 * s1;
                    x0 = n0; x1 = n1; x2 = n2; x3 = n3;
                }
                unsigned short* Cp = (unsigned short*)C + (size_t)row * N + colbase;
                Cp[0]  = f_to_bf16(x0);
                Cp[16] = f_to_bf16(x1);
                Cp[64] = f_to_bf16(x2);
                Cp[80] = f_to_bf16(x3);
            }
    } else {
        int cf32 = c_mode ? !isbf : 0;
        // C/D layout: col = lane&15, row = quad*4 + reg  [m89/m91 verified]
#pragma unroll
        for (int a = 0; a < 2 * MT; ++a)
#pragma unroll
            for (int g = 0; g < 4; ++g)
#pragma unroll
                for (int r = 0; r < 4; ++r) {
                    int row = bm + wr * (MT * 32) + a * 16 + quad * 4 + r;
                    int col = bn + wc * 64 + g * 16 + l16;
                    size_t idx = (size_t)row * N + col;
                    if (cf32) ((float*)C)[idx] = acc[a][g][r];
                    else      ((unsigned short*)C)[idx] = f_to_bf16(acc[a][g][r]);
                }
    }
}

// ---------------------------------------------------------------------------
// Kernel 4: MFMA flash attention (unchanged — verified fast).
// ---------------------------------------------------------------------------
__global__ __launch_bounds__(256, 4) void attn_mfma(const unsigned short* __restrict__ qkv,
                                                    const int* __restrict__ counts,
                                                    const int* __restrict__ poslist,
                                                    unsigned short* __restrict__ o) {
    int qt  = blockIdx.x & 127;
    int kvh = (blockIdx.x >> 7) & 3;
    int s   = (blockIdx.x >> 9) & 7;
    int b   = blockIdx.x >> 12;
    int n = counts[b * NS_ + s];
    if (qt * 16 >= n) return;
    const int* plist = poslist + ((size_t)b * NS_ + s) * L_;

    __shared__ short Ksh[32][136];
    __shared__ short Vsh[128][40];
    __shared__ short Psh[4][16][40];
    __shared__ int posq[16];

    int tid = threadIdx.x;
    int wave = tid >> 6, lane = tid & 63;
    int quad = lane >> 4, l16 = lane & 15;
    int h = kvh * 4 + wave;
    const float scale = 0.08838834764831845f;

    if (tid < 16) posq[tid] = plist[min(qt * 16 + tid, n - 1)];
    __syncthreads();

    short8 qf[4];
    {
        const unsigned short* gq =
            qkv + ((size_t)(b << 11) + posq[l16]) * QKV_N + h * D_;
#pragma unroll
        for (int kk = 0; kk < 4; kk++)
            qf[kk] = *(const short8*)(gq + kk * 32 + quad * 8);
    }

    float m_r[4], l_r[4];
    floatx4 Ov[8];
#pragma unroll
    for (int r4 = 0; r4 < 4; r4++) { m_r[r4] = -1e30f; l_r[r4] = 0.f; }
#pragma unroll
    for (int nt = 0; nt < 8; nt++) Ov[nt] = (floatx4){0.f, 0.f, 0.f, 0.f};

    int c0 = max(0, (qt * 16 - WIN_) >> 5);
    int nch = ((qt * 16 + 15) >> 5) + 1;

    int r = tid >> 3, seg = tid & 7;
    int vc = r ^ ((seg & 3) << 3);
    short8 kr0, kr1, vr0, vr1;
    {
        int kpos = plist[min(c0 * 32 + r, n - 1)];
        size_t base = ((size_t)(b << 11) + kpos) * QKV_N + 2048 + kvh * D_ + seg * 16;
        kr0 = *(const short8*)(qkv + base);
        kr1 = *(const short8*)(qkv + base + 8);
        vr0 = *(const short8*)(qkv + base + 512);
        vr1 = *(const short8*)(qkv + base + 520);
    }

    for (int c = c0; c < nch; c++) {
        *(short8*)&Ksh[r][seg * 16]     = kr0;
        *(short8*)&Ksh[r][seg * 16 + 8] = kr1;
#pragma unroll
        for (int e = 0; e < 8; e++) Vsh[seg * 16 + e][vc] = vr0[e];
#pragma unroll
        for (int e = 0; e < 8; e++) Vsh[seg * 16 + 8 + e][vc] = vr1[e];
        __syncthreads();

        if (c + 1 < nch) {
            int kpos = plist[min((c + 1) * 32 + r, n - 1)];
            size_t base = ((size_t)(b << 11) + kpos) * QKV_N + 2048 + kvh * D_ + seg * 16;
            kr0 = *(const short8*)(qkv + base);
            kr1 = *(const short8*)(qkv + base + 8);
            vr0 = *(const short8*)(qkv + base + 512);
            vr1 = *(const short8*)(qkv + base + 520);
        }

        floatx4 s0 = (floatx4){0.f, 0.f, 0.f, 0.f};
        floatx4 s1 = (floatx4){0.f, 0.f, 0.f, 0.f};
#pragma unroll
        for (int kk = 0; kk < 4; kk++) {
            short8 kfa = *(const short8*)&Ksh[l16][kk * 32 + quad * 8];
            s0 = __builtin_amdgcn_mfma_f32_16x16x32_bf16(qf[kk], kfa, s0, 0, 0, 0);
        }
#pragma unroll
        for (int kk = 0; kk < 4; kk++) {
            short8 kfb = *(const short8*)&Ksh[16 + l16][kk * 32 + quad * 8];
            s1 = __builtin_amdgcn_mfma_f32_16x16x32_bf16(qf[kk], kfb, s1, 0, 0, 0);
        }

        int kr0i = c * 32 + l16, kr1i = kr0i + 16;
        float x0[4], x1[4], rmax[4];
#pragma unroll
        for (int r4 = 0; r4 < 4; r4++) {
            int qr = qt * 16 + quad * 4 + r4;
            bool mk0 = (kr0i <= qr) && (kr0i >= qr - WIN_);
            bool mk1 = (kr1i <= qr) && (kr1i >= qr - WIN_);
            x0[r4] = mk0 ? s0[r4] * scale : -1e30f;
            x1[r4] = mk1 ? s1[r4] * scale : -1e30f;
            rmax[r4] = fmaxf(x0[r4], x1[r4]);
        }
#pragma unroll
        for (int st = 1; st <= 8; st <<= 1)
#pragma unroll
            for (int r4 = 0; r4 < 4; r4++)
                rmax[r4] = fmaxf(rmax[r4], __shfl_xor(rmax[r4], st, 64));
        float al[4], psum[4];
#pragma unroll
        for (int r4 = 0; r4 < 4; r4++) {
            float nm = fmaxf(m_r[r4], rmax[r4]);
            al[r4] = __expf(m_r[r4] - nm);
            m_r[r4] = nm;
            x0[r4] = (x0[r4] > -1e29f) ? __expf(x0[r4] - nm) : 0.f;
            x1[r4] = (x1[r4] > -1e29f) ? __expf(x1[r4] - nm) : 0.f;
            psum[r4] = x0[r4] + x1[r4];
        }
#pragma unroll
        for (int st = 1; st <= 8; st <<= 1)
#pragma unroll
            for (int r4 = 0; r4 < 4; r4++)
                psum[r4] += __shfl_xor(psum[r4], st, 64);
#pragma unroll
        for (int r4 = 0; r4 < 4; r4++) l_r[r4] = l_r[r4] * al[r4] + psum[r4];
#pragma unroll
        for (int nt = 0; nt < 8; nt++)
#pragma unroll
            for (int r4 = 0; r4 < 4; r4++) Ov[nt][r4] *= al[r4];

#pragma unroll
        for (int r4 = 0; r4 < 4; r4++) {
            Psh[wave][quad * 4 + r4][l16]      = (short)f_to_bf16(x0[r4]);
            Psh[wave][quad * 4 + r4][16 + l16] = (short)f_to_bf16(x1[r4]);
        }
        short8 pf = *(const short8*)&Psh[wave][l16][quad * 8];

#pragma unroll
        for (int nt = 0; nt < 8; nt++) {
            short8 vf = *(const short8*)&Vsh[nt * 16 + l16][(quad ^ (nt & 3)) * 8];
            Ov[nt] = __builtin_amdgcn_mfma_f32_16x16x32_bf16(pf, vf, Ov[nt], 0, 0, 0);
        }
        __syncthreads();
    }

    float inv_r[4];
    int pos_r[4], qvalid[4];
#pragma unroll
    for (int r4 = 0; r4 < 4; r4++) {
        int qr = qt * 16 + quad * 4 + r4;
        qvalid[r4] = (qr < n);
        inv_r[r4] = 1.f / l_r[r4];
        pos_r[r4] = posq[quad * 4 + r4];
    }
#pragma unroll
    for (int nt = 0; nt < 8; nt++)
#pragma unroll
        for (int r4 = 0; r4 < 4; r4++)
            if (qvalid[r4])
                o[(((size_t)(b << 11) + pos_r[r4]) * H_ + h) * D_ + nt * 16 + l16] =
                    f_to_bf16(Ov[nt][r4] * inv_r[r4]);
}

// ---------------------------------------------------------------------------
extern "C" void kernel_launch(void* const* d_in, const int* in_sizes, int n_in,
                              void* d_out, int out_size, void* d_ws, size_t ws_size,
                              hipStream_t stream) {
    const void* hs = d_in[0];
    const void* Wq = d_in[1];
    const void* Wk = d_in[2];
    const void* Wv = d_in[3];
    const void* Wo = d_in[4];
    const int* sid  = (const int*)d_in[5];
    const int* pids = (const int*)d_in[6];

    const int M = B_ * L_;  // 4096
    char* w = (char*)d_ws;
    unsigned short* qkv  = (unsigned short*)(w + 256);          // 25,165,824
    unsigned short* o_b  = (unsigned short*)(w + 25166080);     // 16,777,216
    unsigned short* c_hs = (unsigned short*)(w + 41943296);     // 16,777,216
    unsigned short* c_Wq = (unsigned short*)(w + 58720512);     //  8,388,608
    unsigned short* c_Wk = (unsigned short*)(w + 67109120);     //  2,097,152
    unsigned short* c_Wv = (unsigned short*)(w + 69206272);     //  2,097,152
    unsigned short* c_Wo = (unsigned short*)(w + 71303424);     //  8,388,608
    int* rank            = (int*)(w + 79692032);                //     16,384
    int* plist           = (int*)(w + 79708416);                //    131,072
    int* counts          = (int*)(w + 79839488);                //        256

    const unsigned short* hs_probe = (const unsigned short*)hs;

    // dtype canonicalization (fp32 world only; bf16 world early-exits)
    convert_all<<<2048, 256, 0, stream>>>(hs, Wq, Wk, Wv, Wo,
                                          c_hs, c_Wq, c_Wk, c_Wv, c_Wo);

    scan_kernel<<<B_, 256, 0, stream>>>(sid, pids, rank, plist, counts);

    // fused QKV projection + RoPE: BM=256, N = 3072,
    // 256-col tiles [0,8)=Wq, [8,10)=Wk, [10,12)=Wv
    gemm_t<4, true><<<dim3(QKV_N / 256, M / 256), 512, 0, stream>>>(
        c_hs, c_Wq, c_Wk, c_Wv,
        (const unsigned short*)hs, (const unsigned short*)Wq,
        (const unsigned short*)Wk, (const unsigned short*)Wv,
        qkv, M, QKV_N, HID_, 8, 10, hs_probe, 0, pids);

    attn_mfma<<<B_ * NS_ * KVH_ * (L_ / 16), 256, 0, stream>>>(qkv, counts, plist, o_b);

    // O-proj: BM=128 -> 8 x 32 = 256 blocks
    gemm_t<2, false><<<dim3(HID_ / 256, M / 128), 512, 0, stream>>>(
        o_b, c_Wo, c_Wo, c_Wo,
        o_b, (const unsigned short*)Wo, (const unsigned short*)Wo,
        (const unsigned short*)Wo,
        d_out, M, HID_, HID_, 1 << 30, 1 << 30, hs_probe, 1, pids);
}